// Round 3
// baseline (289.969 us; speedup 1.0000x reference)
//
#include <hip/hip_runtime.h>
#include <stdint.h>

// SynapticSNN — ALL tensors are FP32 (reference uses jnp.float32 throughout;
// rounds 0-2 failed because inputs were misread as bf16 -> NaN bit patterns).
// No fp32-input MFMA on CDNA4 -> VALU GEMMs. The 100-step recurrence
// (8.4M neurons x 100 x ~7 ops ~ 75 us) dominates; GEMM1 ~27 us VALU.
// Recurrence uses explicit __f*_rn ops in np's order (no FMA contraction):
// syn = round(0.9*syn)+cur1; mem = ((beta*mem)+syn)-reset, reset from
// PRE-update mem > 1.0. Spikes stored as bf16 {0,1} (exact) in ws.

#define NSTEPS 100

static __device__ __forceinline__ float bf2f(uint16_t b) {
  union { uint32_t u; float f; } v; v.u = ((uint32_t)b) << 16; return v.f;
}

// ---------------------------------------------------------------------------
// Kernel 1: cur1 = X[4096,256] @ W1[2048,256]^T + b1 (fp32 VALU GEMM),
// fused 100-step recurrence, spk (bf16 {0,1}) [4096,2048] -> ws.
// 64x64 tile, 16x16 threads, 4x4 outputs/thread, BK=32, LDS [kk][m] stride 68.
// ---------------------------------------------------------------------------
__global__ __launch_bounds__(256) void snn_k1(
    const float* __restrict__ X, const float* __restrict__ W1,
    const float* __restrict__ b1, const float* __restrict__ betap,
    uint16_t* __restrict__ spk)
{
  __shared__ __align__(16) float As[32 * 68];
  __shared__ __align__(16) float Bs[32 * 68];
  const int tid = threadIdx.x;
  const int bm  = blockIdx.y * 64;   // batch rows
  const int bn  = blockIdx.x * 64;   // hidden cols
  const int ty  = tid >> 4;          // 0..15 -> rows ty*4..+3
  const int tx  = tid & 15;          // 0..15 -> cols tx*4..+3
  const int sc  = tid & 7;           // staging k-group (4 floats)
  const int sr  = tid >> 3;          // staging row 0..31

  float acc[4][4] = {};

  for (int k0 = 0; k0 < 256; k0 += 32) {
    #pragma unroll
    for (int h = 0; h < 2; ++h) {
      const int r = sr + h * 32;
      const float4 xa = *(const float4*)(X  + (size_t)(bm + r) * 256 + k0 + sc * 4);
      const float4 wa = *(const float4*)(W1 + (size_t)(bn + r) * 256 + k0 + sc * 4);
      As[(sc * 4 + 0) * 68 + r] = xa.x;
      As[(sc * 4 + 1) * 68 + r] = xa.y;
      As[(sc * 4 + 2) * 68 + r] = xa.z;
      As[(sc * 4 + 3) * 68 + r] = xa.w;
      Bs[(sc * 4 + 0) * 68 + r] = wa.x;
      Bs[(sc * 4 + 1) * 68 + r] = wa.y;
      Bs[(sc * 4 + 2) * 68 + r] = wa.z;
      Bs[(sc * 4 + 3) * 68 + r] = wa.w;
    }
    __syncthreads();
    #pragma unroll
    for (int kk = 0; kk < 32; ++kk) {
      const float4 a4 = *(const float4*)(As + kk * 68 + ty * 4);
      const float4 b4 = *(const float4*)(Bs + kk * 68 + tx * 4);
      const float av[4] = {a4.x, a4.y, a4.z, a4.w};
      const float bv[4] = {b4.x, b4.y, b4.z, b4.w};
      #pragma unroll
      for (int i = 0; i < 4; ++i)
        #pragma unroll
        for (int j = 0; j < 4; ++j)
          acc[i][j] += av[i] * bv[j];   // FMA ok for GEMM (np-order noise ~1e-6)
    }
    __syncthreads();
  }

  // ---- fused recurrence, np fp32 semantics ----
  float beta = betap[0];
  beta = fminf(fmaxf(beta, 0.0f), 1.0f);
  float bias[4];
  #pragma unroll
  for (int j = 0; j < 4; ++j) bias[j] = b1[bn + tx * 4 + j];

  float cc[16], syn[16], mem[16];
  #pragma unroll
  for (int i = 0; i < 4; ++i)
    #pragma unroll
    for (int j = 0; j < 4; ++j) {
      cc[i * 4 + j]  = acc[i][j] + bias[j];
      syn[i * 4 + j] = 0.0f;
      mem[i * 4 + j] = 0.0f;
    }

  #pragma unroll 1
  for (int t = 0; t < NSTEPS; ++t) {
    #pragma unroll
    for (int e = 0; e < 16; ++e) {
      const float rst = (mem[e] > 1.0f) ? 1.0f : 0.0f;   // pre-update reset
      syn[e] = __fadd_rn(__fmul_rn(0.9f, syn[e]), cc[e]);
      mem[e] = __fsub_rn(__fadd_rn(__fmul_rn(beta, mem[e]), syn[e]), rst);
    }
  }

  #pragma unroll
  for (int i = 0; i < 4; ++i) {
    ushort4 o;
    o.x = (mem[i * 4 + 0] > 1.0f) ? (uint16_t)0x3F80u : (uint16_t)0u;
    o.y = (mem[i * 4 + 1] > 1.0f) ? (uint16_t)0x3F80u : (uint16_t)0u;
    o.z = (mem[i * 4 + 2] > 1.0f) ? (uint16_t)0x3F80u : (uint16_t)0u;
    o.w = (mem[i * 4 + 3] > 1.0f) ? (uint16_t)0x3F80u : (uint16_t)0u;
    *(ushort4*)(spk + (size_t)(bm + ty * 4 + i) * 2048 + bn + tx * 4) = o;
  }
}

// ---------------------------------------------------------------------------
// Kernel 2: out[4096,128] = spk @ W2[128,2048]^T + b2 (fp32 VALU).
// 16x128 tile per block, 256 blocks, BK=32. Thread: 2 rows x 4 cols.
// ---------------------------------------------------------------------------
__global__ __launch_bounds__(256) void snn_k2(
    const uint16_t* __restrict__ spk, const float* __restrict__ W2,
    const float* __restrict__ b2, float* __restrict__ out)
{
  __shared__ __align__(16) float Ss[32 * 20];    // [kk][m], stride 20
  __shared__ __align__(16) float Ws[32 * 132];   // [kk][n], stride 132
  const int tid = threadIdx.x;
  const int bm  = blockIdx.x * 16;
  const int ty  = tid >> 5;    // 0..7 -> rows ty*2, ty*2+1
  const int tx  = tid & 31;    // 0..31 -> cols tx*4..+3

  float acc[2][4] = {};

  for (int k0 = 0; k0 < 2048; k0 += 32) {
    if (tid < 128) {
      const int c = tid & 7, r = tid >> 3;     // r 0..15
      const ushort4 v = *(const ushort4*)(spk + (size_t)(bm + r) * 2048 + k0 + c * 4);
      Ss[(c * 4 + 0) * 20 + r] = bf2f(v.x);
      Ss[(c * 4 + 1) * 20 + r] = bf2f(v.y);
      Ss[(c * 4 + 2) * 20 + r] = bf2f(v.z);
      Ss[(c * 4 + 3) * 20 + r] = bf2f(v.w);
    }
    #pragma unroll
    for (int it = 0; it < 4; ++it) {
      const int u = it * 256 + tid;
      const int n = u >> 3, c = u & 7;         // n 0..127
      const float4 wv = *(const float4*)(W2 + (size_t)n * 2048 + k0 + c * 4);
      Ws[(c * 4 + 0) * 132 + n] = wv.x;
      Ws[(c * 4 + 1) * 132 + n] = wv.y;
      Ws[(c * 4 + 2) * 132 + n] = wv.z;
      Ws[(c * 4 + 3) * 132 + n] = wv.w;
    }
    __syncthreads();
    #pragma unroll
    for (int kk = 0; kk < 32; ++kk) {
      const float2 s2 = *(const float2*)(Ss + kk * 20 + ty * 2);
      const float4 w4 = *(const float4*)(Ws + kk * 132 + tx * 4);
      acc[0][0] += s2.x * w4.x;  acc[0][1] += s2.x * w4.y;
      acc[0][2] += s2.x * w4.z;  acc[0][3] += s2.x * w4.w;
      acc[1][0] += s2.y * w4.x;  acc[1][1] += s2.y * w4.y;
      acc[1][2] += s2.y * w4.z;  acc[1][3] += s2.y * w4.w;
    }
    __syncthreads();
  }

  #pragma unroll
  for (int i = 0; i < 2; ++i) {
    const int row = bm + ty * 2 + i;
    float4 o;
    o.x = acc[i][0] + b2[tx * 4 + 0];
    o.y = acc[i][1] + b2[tx * 4 + 1];
    o.z = acc[i][2] + b2[tx * 4 + 2];
    o.w = acc[i][3] + b2[tx * 4 + 3];
    *(float4*)(out + (size_t)row * 128 + tx * 4) = o;
  }
}

extern "C" void kernel_launch(void* const* d_in, const int* in_sizes, int n_in,
                              void* d_out, int out_size, void* d_ws, size_t ws_size,
                              hipStream_t stream) {
  const float* X    = (const float*)d_in[0];  // [4096,256]
  const float* W1   = (const float*)d_in[1];  // [2048,256]
  const float* b1   = (const float*)d_in[2];  // [2048]
  const float* W2   = (const float*)d_in[3];  // [128,2048]
  const float* b2   = (const float*)d_in[4];  // [128]
  const float* beta = (const float*)d_in[5];  // scalar
  float* out = (float*)d_out;                 // [4096,128] fp32

  uint16_t* spk = (uint16_t*)d_ws;            // 16 MiB bf16 {0,1}

  snn_k1<<<dim3(32, 64), 256, 0, stream>>>(X, W1, b1, beta, spk);
  snn_k2<<<256, 256, 0, stream>>>(spk, W2, b2, out);
}

// Round 4
// 235.795 us; speedup vs baseline: 1.2298x; 1.2298x over previous
//
#include <hip/hip_runtime.h>
#include <stdint.h>

// SynapticSNN — all fp32. cur1 = X@W1^T + b1 (VALU GEMM, no fp32 MFMA on
// CDNA4), fused 100-step recurrence with EXACT np fp32 op order (no FMA
// contraction: syn = rn(rn(0.9*syn)+cc); mem = rn(rn(rn(b*mem)+syn)-rst),
// rst from PRE-update mem > 1). Spikes bf16 {0,1} (exact) -> ws.
// R3 fixes: (a) k1 __launch_bounds__(256,4): R2's VGPR_Count=36 < 48 live
// recurrence floats -> AGPR spill traffic in the t-loop (~29 us). 128-VGPR
// cap removes it at unchanged occupancy. (b) k2 was 1 wave/SIMD (256 blocks)
// -> latency-bound ~130 us; now split-K=8, 1024 blocks, partials + reduce.

#define NSTEPS 100

static __device__ __forceinline__ float bf2f(uint16_t b) {
  union { uint32_t u; float f; } v; v.u = ((uint32_t)b) << 16; return v.f;
}

// ---------------------------------------------------------------------------
// Kernel 1: cur1 GEMM + recurrence -> spk. 64x64 tile, 4x4/thread, BK=32.
// ---------------------------------------------------------------------------
__global__ __launch_bounds__(256, 4) void snn_k1(
    const float* __restrict__ X, const float* __restrict__ W1,
    const float* __restrict__ b1, const float* __restrict__ betap,
    uint16_t* __restrict__ spk)
{
  __shared__ __align__(16) float As[32 * 68];
  __shared__ __align__(16) float Bs[32 * 68];
  const int tid = threadIdx.x;
  const int bm  = blockIdx.y * 64;   // batch rows
  const int bn  = blockIdx.x * 64;   // hidden cols
  const int ty  = tid >> 4;          // 0..15 -> rows ty*4..+3
  const int tx  = tid & 15;          // 0..15 -> cols tx*4..+3
  const int sc  = tid & 7;           // staging k-group (4 floats)
  const int sr  = tid >> 3;          // staging row 0..31

  float acc[4][4] = {};

  for (int k0 = 0; k0 < 256; k0 += 32) {
    #pragma unroll
    for (int h = 0; h < 2; ++h) {
      const int r = sr + h * 32;
      const float4 xa = *(const float4*)(X  + (size_t)(bm + r) * 256 + k0 + sc * 4);
      const float4 wa = *(const float4*)(W1 + (size_t)(bn + r) * 256 + k0 + sc * 4);
      As[(sc * 4 + 0) * 68 + r] = xa.x;
      As[(sc * 4 + 1) * 68 + r] = xa.y;
      As[(sc * 4 + 2) * 68 + r] = xa.z;
      As[(sc * 4 + 3) * 68 + r] = xa.w;
      Bs[(sc * 4 + 0) * 68 + r] = wa.x;
      Bs[(sc * 4 + 1) * 68 + r] = wa.y;
      Bs[(sc * 4 + 2) * 68 + r] = wa.z;
      Bs[(sc * 4 + 3) * 68 + r] = wa.w;
    }
    __syncthreads();
    #pragma unroll
    for (int kk = 0; kk < 32; ++kk) {
      const float4 a4 = *(const float4*)(As + kk * 68 + ty * 4);
      const float4 b4 = *(const float4*)(Bs + kk * 68 + tx * 4);
      const float av[4] = {a4.x, a4.y, a4.z, a4.w};
      const float bv[4] = {b4.x, b4.y, b4.z, b4.w};
      #pragma unroll
      for (int i = 0; i < 4; ++i)
        #pragma unroll
        for (int j = 0; j < 4; ++j)
          acc[i][j] += av[i] * bv[j];
    }
    __syncthreads();
  }

  // ---- fused recurrence, np fp32 semantics ----
  float beta = betap[0];
  beta = fminf(fmaxf(beta, 0.0f), 1.0f);
  float bias[4];
  #pragma unroll
  for (int j = 0; j < 4; ++j) bias[j] = b1[bn + tx * 4 + j];

  float cc[16], syn[16], mem[16];
  #pragma unroll
  for (int i = 0; i < 4; ++i)
    #pragma unroll
    for (int j = 0; j < 4; ++j) {
      cc[i * 4 + j]  = acc[i][j] + bias[j];
      syn[i * 4 + j] = 0.0f;
      mem[i * 4 + j] = 0.0f;
    }

  #pragma unroll 1
  for (int t = 0; t < NSTEPS; ++t) {
    #pragma unroll
    for (int e = 0; e < 16; ++e) {
      const float rst = (mem[e] > 1.0f) ? 1.0f : 0.0f;   // pre-update reset
      syn[e] = __fadd_rn(__fmul_rn(0.9f, syn[e]), cc[e]);
      mem[e] = __fsub_rn(__fadd_rn(__fmul_rn(beta, mem[e]), syn[e]), rst);
    }
  }

  #pragma unroll
  for (int i = 0; i < 4; ++i) {
    ushort4 o;
    o.x = (mem[i * 4 + 0] > 1.0f) ? (uint16_t)0x3F80u : (uint16_t)0u;
    o.y = (mem[i * 4 + 1] > 1.0f) ? (uint16_t)0x3F80u : (uint16_t)0u;
    o.z = (mem[i * 4 + 2] > 1.0f) ? (uint16_t)0x3F80u : (uint16_t)0u;
    o.w = (mem[i * 4 + 3] > 1.0f) ? (uint16_t)0x3F80u : (uint16_t)0u;
    *(ushort4*)(spk + (size_t)(bm + ty * 4 + i) * 2048 + bn + tx * 4) = o;
  }
}

// ---------------------------------------------------------------------------
// Kernel 2: split-K GEMM2 partials. Block: 32 rows x 128 cols, K-chunk 256
// (BK=32, 8 tiles). Grid 128 x 8. part[kc][4096][128] fp32 -> ws.
// ---------------------------------------------------------------------------
__global__ __launch_bounds__(256) void snn_k2(
    const uint16_t* __restrict__ spk, const float* __restrict__ W2,
    float* __restrict__ part)
{
  __shared__ __align__(16) float Ss[32 * 36];    // [kk][m], stride 36
  __shared__ __align__(16) float Ws[32 * 132];   // [kk][n], stride 132
  const int tid = threadIdx.x;
  const int bm  = blockIdx.x * 32;
  const int kc  = blockIdx.y;          // K chunk of 256
  const int ty  = tid >> 5;            // 0..7  -> rows ty*4..+3
  const int tx  = tid & 31;            // 0..31 -> cols tx*4..+3

  float acc[4][4] = {};

  for (int k0 = kc * 256; k0 < kc * 256 + 256; k0 += 32) {
    {
      const int r = tid >> 3, c = tid & 7;     // r 0..31, c 0..7
      const ushort4 v = *(const ushort4*)(spk + (size_t)(bm + r) * 2048 + k0 + c * 4);
      Ss[(c * 4 + 0) * 36 + r] = bf2f(v.x);
      Ss[(c * 4 + 1) * 36 + r] = bf2f(v.y);
      Ss[(c * 4 + 2) * 36 + r] = bf2f(v.z);
      Ss[(c * 4 + 3) * 36 + r] = bf2f(v.w);
    }
    #pragma unroll
    for (int it = 0; it < 4; ++it) {
      const int u = it * 256 + tid;
      const int n = u >> 3, c = u & 7;         // n 0..127
      const float4 wv = *(const float4*)(W2 + (size_t)n * 2048 + k0 + c * 4);
      Ws[(c * 4 + 0) * 132 + n] = wv.x;
      Ws[(c * 4 + 1) * 132 + n] = wv.y;
      Ws[(c * 4 + 2) * 132 + n] = wv.z;
      Ws[(c * 4 + 3) * 132 + n] = wv.w;
    }
    __syncthreads();
    #pragma unroll
    for (int kk = 0; kk < 32; ++kk) {
      const float4 a4 = *(const float4*)(Ss + kk * 36 + ty * 4);
      const float4 b4 = *(const float4*)(Ws + kk * 132 + tx * 4);
      const float av[4] = {a4.x, a4.y, a4.z, a4.w};
      const float bv[4] = {b4.x, b4.y, b4.z, b4.w};
      #pragma unroll
      for (int i = 0; i < 4; ++i)
        #pragma unroll
        for (int j = 0; j < 4; ++j)
          acc[i][j] += av[i] * bv[j];
    }
    __syncthreads();
  }

  #pragma unroll
  for (int i = 0; i < 4; ++i) {
    float4 o;
    o.x = acc[i][0]; o.y = acc[i][1]; o.z = acc[i][2]; o.w = acc[i][3];
    *(float4*)(part + ((size_t)kc * 4096 + bm + ty * 4 + i) * 128 + tx * 4) = o;
  }
}

// ---------------------------------------------------------------------------
// Kernel 3: out[m][n] = sum_kc part[kc][m][n] + b2[n]  (fp32 out)
// ---------------------------------------------------------------------------
__global__ __launch_bounds__(256) void snn_k3(
    const float* __restrict__ part, const float* __restrict__ b2,
    float* __restrict__ out)
{
  const int idx = blockIdx.x * 256 + threadIdx.x;   // 131072 threads, 4 cols ea
  const int m = idx >> 5;
  const int c = (idx & 31) << 2;
  float s0 = 0.f, s1 = 0.f, s2 = 0.f, s3 = 0.f;
  #pragma unroll
  for (int kc = 0; kc < 8; ++kc) {
    const float4 p = *(const float4*)(part + ((size_t)kc * 4096 + m) * 128 + c);
    s0 += p.x; s1 += p.y; s2 += p.z; s3 += p.w;
  }
  float4 o;
  o.x = s0 + b2[c + 0];
  o.y = s1 + b2[c + 1];
  o.z = s2 + b2[c + 2];
  o.w = s3 + b2[c + 3];
  *(float4*)(out + (size_t)m * 128 + c) = o;
}

extern "C" void kernel_launch(void* const* d_in, const int* in_sizes, int n_in,
                              void* d_out, int out_size, void* d_ws, size_t ws_size,
                              hipStream_t stream) {
  const float* X    = (const float*)d_in[0];  // [4096,256]
  const float* W1   = (const float*)d_in[1];  // [2048,256]
  const float* b1   = (const float*)d_in[2];  // [2048]
  const float* W2   = (const float*)d_in[3];  // [128,2048]
  const float* b2   = (const float*)d_in[4];  // [128]
  const float* beta = (const float*)d_in[5];  // scalar
  float* out = (float*)d_out;                 // [4096,128] fp32

  uint16_t* spk = (uint16_t*)d_ws;                               // 16 MiB
  float* part = (float*)((char*)d_ws + (size_t)4096 * 2048 * 2); // 16 MiB

  snn_k1<<<dim3(32, 64), 256, 0, stream>>>(X, W1, b1, beta, spk);
  snn_k2<<<dim3(128, 8), 256, 0, stream>>>(spk, W2, part);
  snn_k3<<<512, 256, 0, stream>>>(part, b2, out);
}

// Round 5
// 233.280 us; speedup vs baseline: 1.2430x; 1.0108x over previous
//
#include <hip/hip_runtime.h>
#include <stdint.h>

// SynapticSNN — all fp32. cur1 = X@W1^T + b1 (VALU GEMM, no fp32 MFMA on
// CDNA4), fused 100-step recurrence with EXACT np fp32 op order (no FMA
// contraction), out = spk@W2^T + b2 (split-K=8 + reduce).
// R4 findings: VGPR_Count=36 persisted under launch_bounds(256,4) -> the
// 48-float recurrence state lives in AGPRs (unified file, not in VGPR_Count)
// and the t-loop pays v_accvgpr shuttles (~28 us of the 130 us VALU-busy).
// R4 fixes: (a) recurrence split into TWO sequential 100-step loops over 8
// elements each (live set ~34 floats -> pure VGPR, no shuttles);
// (b) k2 software-pipelined: prefetch next tile's globals into registers
// during current tile's compute (staging latency was serialized across 16
// barriers at only 4 waves/SIMD).

#define NSTEPS 100

static __device__ __forceinline__ float bf2f(uint16_t b) {
  union { uint32_t u; float f; } v; v.u = ((uint32_t)b) << 16; return v.f;
}

// ---------------------------------------------------------------------------
// Kernel 1: cur1 GEMM + recurrence -> spk. 64x64 tile, 4x4/thread, BK=32.
// ---------------------------------------------------------------------------
__global__ __launch_bounds__(256, 4) void snn_k1(
    const float* __restrict__ X, const float* __restrict__ W1,
    const float* __restrict__ b1, const float* __restrict__ betap,
    uint16_t* __restrict__ spk)
{
  __shared__ __align__(16) float As[32 * 68];
  __shared__ __align__(16) float Bs[32 * 68];
  const int tid = threadIdx.x;
  const int bm  = blockIdx.y * 64;   // batch rows
  const int bn  = blockIdx.x * 64;   // hidden cols
  const int ty  = tid >> 4;          // 0..15 -> rows ty*4..+3
  const int tx  = tid & 15;          // 0..15 -> cols tx*4..+3
  const int sc  = tid & 7;           // staging k-group (4 floats)
  const int sr  = tid >> 3;          // staging row 0..31

  float acc[4][4] = {};

  for (int k0 = 0; k0 < 256; k0 += 32) {
    #pragma unroll
    for (int h = 0; h < 2; ++h) {
      const int r = sr + h * 32;
      const float4 xa = *(const float4*)(X  + (size_t)(bm + r) * 256 + k0 + sc * 4);
      const float4 wa = *(const float4*)(W1 + (size_t)(bn + r) * 256 + k0 + sc * 4);
      As[(sc * 4 + 0) * 68 + r] = xa.x;
      As[(sc * 4 + 1) * 68 + r] = xa.y;
      As[(sc * 4 + 2) * 68 + r] = xa.z;
      As[(sc * 4 + 3) * 68 + r] = xa.w;
      Bs[(sc * 4 + 0) * 68 + r] = wa.x;
      Bs[(sc * 4 + 1) * 68 + r] = wa.y;
      Bs[(sc * 4 + 2) * 68 + r] = wa.z;
      Bs[(sc * 4 + 3) * 68 + r] = wa.w;
    }
    __syncthreads();
    #pragma unroll
    for (int kk = 0; kk < 32; ++kk) {
      const float4 a4 = *(const float4*)(As + kk * 68 + ty * 4);
      const float4 b4 = *(const float4*)(Bs + kk * 68 + tx * 4);
      const float av[4] = {a4.x, a4.y, a4.z, a4.w};
      const float bv[4] = {b4.x, b4.y, b4.z, b4.w};
      #pragma unroll
      for (int i = 0; i < 4; ++i)
        #pragma unroll
        for (int j = 0; j < 4; ++j)
          acc[i][j] += av[i] * bv[j];
    }
    __syncthreads();
  }

  // ---- fused recurrence, np fp32 semantics, 2 x 8-element passes ----
  float beta = betap[0];
  beta = fminf(fmaxf(beta, 0.0f), 1.0f);
  float bias[4];
  #pragma unroll
  for (int j = 0; j < 4; ++j) bias[j] = b1[bn + tx * 4 + j];

  float cc[16];
  #pragma unroll
  for (int i = 0; i < 4; ++i)
    #pragma unroll
    for (int j = 0; j < 4; ++j)
      cc[i * 4 + j] = acc[i][j] + bias[j];

  #pragma unroll
  for (int h = 0; h < 2; ++h) {          // half h: elements h*8 .. h*8+7
    float syn[8], mem[8];
    #pragma unroll
    for (int e = 0; e < 8; ++e) { syn[e] = 0.0f; mem[e] = 0.0f; }

    #pragma unroll 1
    for (int t = 0; t < NSTEPS; ++t) {
      #pragma unroll
      for (int e = 0; e < 8; ++e) {
        const float rst = (mem[e] > 1.0f) ? 1.0f : 0.0f;   // pre-update reset
        syn[e] = __fadd_rn(__fmul_rn(0.9f, syn[e]), cc[h * 8 + e]);
        mem[e] = __fsub_rn(__fadd_rn(__fmul_rn(beta, mem[e]), syn[e]), rst);
      }
    }

    #pragma unroll
    for (int i = 0; i < 2; ++i) {        // rows h*2+i of this thread's 4x4
      ushort4 o;
      o.x = (mem[i * 4 + 0] > 1.0f) ? (uint16_t)0x3F80u : (uint16_t)0u;
      o.y = (mem[i * 4 + 1] > 1.0f) ? (uint16_t)0x3F80u : (uint16_t)0u;
      o.z = (mem[i * 4 + 2] > 1.0f) ? (uint16_t)0x3F80u : (uint16_t)0u;
      o.w = (mem[i * 4 + 3] > 1.0f) ? (uint16_t)0x3F80u : (uint16_t)0u;
      *(ushort4*)(spk + (size_t)(bm + ty * 4 + h * 2 + i) * 2048 + bn + tx * 4) = o;
    }
  }
}

// ---------------------------------------------------------------------------
// Kernel 2: split-K GEMM2 partials, software-pipelined staging.
// Block: 32 rows x 128 cols, K-chunk 256 (8 tiles of BK=32). Grid 128 x 8.
// ---------------------------------------------------------------------------
__global__ __launch_bounds__(256) void snn_k2(
    const uint16_t* __restrict__ spk, const float* __restrict__ W2,
    float* __restrict__ part)
{
  __shared__ __align__(16) float Ss[32 * 36];    // [kk][m], stride 36
  __shared__ __align__(16) float Ws[32 * 132];   // [kk][n], stride 132
  const int tid = threadIdx.x;
  const int bm  = blockIdx.x * 32;
  const int kc  = blockIdx.y;          // K chunk of 256
  const int ty  = tid >> 5;            // 0..7  -> rows ty*4..+3
  const int tx  = tid & 31;            // 0..31 -> cols tx*4..+3
  const int sr  = tid >> 3, sc = tid & 7;   // spk staging: row 0..31, chunk 0..7

  float acc[4][4] = {};

  // prefetch tile 0
  int k0 = kc * 256;
  ushort4 ps = *(const ushort4*)(spk + (size_t)(bm + sr) * 2048 + k0 + sc * 4);
  float4 pw[4];
  #pragma unroll
  for (int it = 0; it < 4; ++it) {
    const int u = it * 256 + tid;
    pw[it] = *(const float4*)(W2 + (size_t)(u >> 3) * 2048 + k0 + (u & 7) * 4);
  }

  #pragma unroll 1
  for (int tile = 0; tile < 8; ++tile) {
    // commit prefetched regs to LDS
    Ss[(sc * 4 + 0) * 36 + sr] = bf2f(ps.x);
    Ss[(sc * 4 + 1) * 36 + sr] = bf2f(ps.y);
    Ss[(sc * 4 + 2) * 36 + sr] = bf2f(ps.z);
    Ss[(sc * 4 + 3) * 36 + sr] = bf2f(ps.w);
    #pragma unroll
    for (int it = 0; it < 4; ++it) {
      const int u = it * 256 + tid;
      const int n = u >> 3, c = u & 7;
      Ws[(c * 4 + 0) * 132 + n] = pw[it].x;
      Ws[(c * 4 + 1) * 132 + n] = pw[it].y;
      Ws[(c * 4 + 2) * 132 + n] = pw[it].z;
      Ws[(c * 4 + 3) * 132 + n] = pw[it].w;
    }
    __syncthreads();

    // issue next tile's loads (overlap with compute below)
    if (tile < 7) {
      const int kn = k0 + 32;
      ps = *(const ushort4*)(spk + (size_t)(bm + sr) * 2048 + kn + sc * 4);
      #pragma unroll
      for (int it = 0; it < 4; ++it) {
        const int u = it * 256 + tid;
        pw[it] = *(const float4*)(W2 + (size_t)(u >> 3) * 2048 + kn + (u & 7) * 4);
      }
      k0 = kn;
    }

    #pragma unroll
    for (int kk = 0; kk < 32; ++kk) {
      const float4 a4 = *(const float4*)(Ss + kk * 36 + ty * 4);
      const float4 b4 = *(const float4*)(Ws + kk * 132 + tx * 4);
      const float av[4] = {a4.x, a4.y, a4.z, a4.w};
      const float bv[4] = {b4.x, b4.y, b4.z, b4.w};
      #pragma unroll
      for (int i = 0; i < 4; ++i)
        #pragma unroll
        for (int j = 0; j < 4; ++j)
          acc[i][j] += av[i] * bv[j];
    }
    __syncthreads();
  }

  #pragma unroll
  for (int i = 0; i < 4; ++i) {
    float4 o;
    o.x = acc[i][0]; o.y = acc[i][1]; o.z = acc[i][2]; o.w = acc[i][3];
    *(float4*)(part + ((size_t)kc * 4096 + bm + ty * 4 + i) * 128 + tx * 4) = o;
  }
}

// ---------------------------------------------------------------------------
// Kernel 3: out[m][n] = sum_kc part[kc][m][n] + b2[n]  (fp32 out)
// ---------------------------------------------------------------------------
__global__ __launch_bounds__(256) void snn_k3(
    const float* __restrict__ part, const float* __restrict__ b2,
    float* __restrict__ out)
{
  const int idx = blockIdx.x * 256 + threadIdx.x;   // 131072 threads, 4 cols ea
  const int m = idx >> 5;
  const int c = (idx & 31) << 2;
  float s0 = 0.f, s1 = 0.f, s2 = 0.f, s3 = 0.f;
  #pragma unroll
  for (int kc = 0; kc < 8; ++kc) {
    const float4 p = *(const float4*)(part + ((size_t)kc * 4096 + m) * 128 + c);
    s0 += p.x; s1 += p.y; s2 += p.z; s3 += p.w;
  }
  float4 o;
  o.x = s0 + b2[c + 0];
  o.y = s1 + b2[c + 1];
  o.z = s2 + b2[c + 2];
  o.w = s3 + b2[c + 3];
  *(float4*)(out + (size_t)m * 128 + c) = o;
}

extern "C" void kernel_launch(void* const* d_in, const int* in_sizes, int n_in,
                              void* d_out, int out_size, void* d_ws, size_t ws_size,
                              hipStream_t stream) {
  const float* X    = (const float*)d_in[0];  // [4096,256]
  const float* W1   = (const float*)d_in[1];  // [2048,256]
  const float* b1   = (const float*)d_in[2];  // [2048]
  const float* W2   = (const float*)d_in[3];  // [128,2048]
  const float* b2   = (const float*)d_in[4];  // [128]
  const float* beta = (const float*)d_in[5];  // scalar
  float* out = (float*)d_out;                 // [4096,128] fp32

  uint16_t* spk = (uint16_t*)d_ws;                               // 16 MiB
  float* part = (float*)((char*)d_ws + (size_t)4096 * 2048 * 2); // 16 MiB

  snn_k1<<<dim3(32, 64), 256, 0, stream>>>(X, W1, b1, beta, spk);
  snn_k2<<<dim3(128, 8), 256, 0, stream>>>(spk, W2, part);
  snn_k3<<<512, 256, 0, stream>>>(part, b2, out);
}